// Round 15
// baseline (379.404 us; speedup 1.0000x reference)
//
#include <hip/hip_runtime.h>
#include <math.h>

// (P, C, NX, NY, NT) = (2, 1, 128, 128, 8), T = 128
// Layout: idx = pp<<17 | X<<10 | Y<<3 | T
#define NSITES (2 * 128 * 128 * 8)      // 262144
#define NBLK   256                      // 16 bx * 8 by * 2 pp
#define NEPOCH 32                       // 32 epochs x 4 fused steps = 128
#define TLX    16                       // staged tile x: 8 own + 4+4 halo
#define TLY    24                       // staged tile y: 16 own + 4+4 halo
#define TSITES (TLX * TLY * 8)          // 3072 staged sites, 3 per thread

#define AGENT __HIP_MEMORY_SCOPE_AGENT

union P2 { float f[2]; unsigned long long u; };
struct St { float x0, p, q0, q1, q2, xb; };

__device__ __forceinline__ unsigned bf_rnd(float v) {
    const unsigned u = __float_as_uint(v);
    return (u + 0x7FFFu + ((u >> 16) & 1u)) >> 16;
}
__device__ __forceinline__ float bf_lo(unsigned p) { return __uint_as_float(p << 16); }
__device__ __forceinline__ float bf_hi(unsigned p) { return __uint_as_float(p & 0xFFFF0000u); }
__device__ __forceinline__ unsigned pk_bf2(float lo, float hi) {
    return bf_rnd(lo) | (bf_rnd(hi) << 16);
}
__device__ __forceinline__ unsigned long long pk_bf4(float a, float b, float c, float d) {
    return (unsigned long long)pk_bf2(a, b) | ((unsigned long long)pk_bf2(c, d) << 32);
}

// R3's proven tree barrier: 1 poller/block, s_sleep backoff, 16-block leaves.
__device__ __forceinline__ void gridbar(unsigned* __restrict__ bar, unsigned step) {
    __syncthreads();  // drains each wave's vmcnt: agent stores are at the coherence point
    if (threadIdx.x == 0) {
        unsigned* leaf = bar + ((blockIdx.x >> 4) << 4);
        unsigned* root = bar + 512;
        unsigned* flag = bar + 576;
        const unsigned old = __hip_atomic_fetch_add(leaf, 1u, __ATOMIC_RELEASE, AGENT);
        if (old + 1u == 16u * step) {
            const unsigned r = __hip_atomic_fetch_add(root, 1u, __ATOMIC_RELAXED, AGENT);
            if (r + 1u == 16u * step) {
                __hip_atomic_store(flag, step, __ATOMIC_RELAXED, AGENT);
            }
        }
        while (__hip_atomic_load(flag, __ATOMIC_RELAXED, AGENT) < step) {
            __builtin_amdgcn_s_sleep(1);
        }
    }
    __syncthreads();
}

// Persistent kernel: 32 epochs x (R14's 4-step 2-D tile). Own-tile state and
// all read-only fields live in registers for the whole run; only the halo
// ring crosses the MALL each epoch (43 B/site vs R6's 88). Sync = tree
// barrier; D1/D2 ping-pong by epoch parity (one full barrier separates any
// ring read of slot s from the next write of slot s).
__global__ __launch_bounds__(1024, 4) void pdhg_persist(
    const float* __restrict__ x,
    const float* __restrict__ lam,
    const float* __restrict__ tau_p,
    const float* __restrict__ sigma_p,
    const float* __restrict__ theta_p,
    unsigned long long* __restrict__ D1,   // 2 slots * NSITES bf16x4 {xb,q0,q1,q2}
    unsigned long long* __restrict__ D2,   // 2 slots * NSITES fp32x2 {p,x0}
    unsigned* __restrict__ bar,
    float* __restrict__ out)
{
    __shared__ float    Lxb[2][TSITES];   // 24 KB
    __shared__ unsigned Lqq[2][TSITES];   // 24 KB  bf16x2 {q0,q1}

    // XCD-arc swizzle (L2-locality heuristic only)
    const int b  = 32 * (blockIdx.x & 7) + (blockIdx.x >> 3);
    const int u  = threadIdx.x;
    const int pp = b >> 7;
    const int rr = b & 127;
    const int bx = rr >> 3;        // [0,16)
    const int by = rr & 7;         // [0,8)

    const int T    = u & 7;
    const int lx   = (u >> 3) & 15;    // [0,16)
    const int ly0  = u >> 7;           // [0,4... 8); slice s has ly = ly0 + 8s
    const int lane = u & 63;
    const int src_tm = (lane & 0x38) | ((T + 7) & 7);
    const int src_tp = (lane & 0x38) | ((T + 1) & 7);

    const int X  = ((bx << 3) + lx - 4) & 127;
    const int Xm = (X + 127) & 127;

    const bool cx = (lx >= 1 && lx < 15);

    int gidx[3];
    bool comp[3], own[3];
    float xn[3], lamc[3], lamx[3], lamy[3], lamt[3];
    #pragma unroll
    for (int s = 0; s < 3; ++s) {
        const int ly = ly0 + 8 * s;
        const int Y  = ((by << 4) + ly - 4) & 127;
        const int Ym = (Y + 127) & 127;
        gidx[s] = (pp << 17) | (X << 10) | (Y << 3) | T;
        const int gxm = (pp << 17) | (Xm << 10) | (Y  << 3) | T;
        const int gym = (pp << 17) | (X  << 10) | (Ym << 3) | T;
        comp[s] = cx && (ly >= 1) && (ly < 23);
        own[s]  = (lx >= 4 && lx < 12 && ly >= 4 && ly < 20);
        xn[s]   = x[gidx[s]];                       // loaded ONCE per kernel
        lamc[s] = comp[s] ? lam[gidx[s]] : 0.f;
        lamx[s] = comp[s] ? lam[gxm] : 0.f;
        lamy[s] = comp[s] ? lam[gym] : 0.f;
    }
    #pragma unroll
    for (int s = 0; s < 3; ++s) lamt[s] = __shfl(lamc[s], src_tm, 64);

    const float L = 3.605551275463989f;  // sqrt(13)
    const float s_sig = (1.f / (1.f + __expf(-sigma_p[0]))) / L;
    const float s_tau = (1.f / (1.f + __expf(-tau_p[0]))) / L;
    const float s_th  =  1.f / (1.f + __expf(-theta_p[0]));
    const float inv1s = 1.f / (1.f + s_sig);

    auto clip = [](float v, float l) { return fmaxf(-l, fminf(l, v)); };
    auto upd = [&](const St& s, float xn_,
                   float xbxp, float xbxm, float xbyp, float xbym,
                   float xbtp, float xbtm,
                   float q0xm, float q1ym, float q2tm,
                   float lc, float lX, float lY, float lT) -> St {
        const float pn  = (s.p + s_sig * (s.xb - xn_)) * inv1s;
        const float q0n = clip(s.q0 + s_sig * (xbxp - s.xb), lc);
        const float q1n = clip(s.q1 + s_sig * (xbyp - s.xb), lc);
        const float q2n = clip(s.q2 + s_sig * (xbtp - s.xb), lc);
        const float q0m = clip(q0xm + s_sig * (s.xb - xbxm), lX);
        const float q1m = clip(q1ym + s_sig * (s.xb - xbym), lY);
        const float q2m = clip(q2tm + s_sig * (s.xb - xbtm), lT);
        const float dv  = (q0m - q0n) + (q1m - q1n) + (q2m - q2n);
        const float x1  = s.x0 - s_tau * (pn + dv);
        return St{ x1, pn, q0n, q1n, q2n, x1 + s_th * (x1 - s.x0) };
    };

    St S[3];

    // substep (R14-proven): compute lx in [4-h,12+h), ly in [4-h,20+h);
    // store-mask = region(h+1); double-buffered LDS, one barrier per sub-step.
    auto substep = [&](int h) {
        const int pb = h & 1;
        #pragma unroll
        for (int s = 0; s < 3; ++s) {
            const int ly = ly0 + 8 * s;
            if (ly < 3 - h || ly >= 21 + h) continue;        // wave-uniform skip
            if (lx >= 3 - h && lx < 13 + h) {
                const int f = u + (s << 10);
                Lxb[pb][f] = S[s].xb;
                Lqq[pb][f] = pk_bf2(S[s].q0, S[s].q1);
            }
        }
        __syncthreads();
        #pragma unroll
        for (int s = 0; s < 3; ++s) {
            const int ly = ly0 + 8 * s;
            if (ly < 4 - h || ly >= 20 + h) continue;        // wave-uniform skip
            const float xbtp = __shfl(S[s].xb, src_tp, 64);
            const float xbtm = __shfl(S[s].xb, src_tm, 64);
            const float q2tm = __shfl(S[s].q2, src_tm, 64);
            if (lx >= 4 - h && lx < 12 + h) {
                const int f = u + (s << 10);
                S[s] = upd(S[s], xn[s],
                           Lxb[pb][f + 8], Lxb[pb][f - 8],
                           Lxb[pb][f + 128], Lxb[pb][f - 128],
                           xbtp, xbtm,
                           bf_lo(Lqq[pb][f - 8]), bf_hi(Lqq[pb][f - 128]), q2tm,
                           lamc[s], lamx[s], lamy[s], lamt[s]);
            }
        }
    };

    #pragma unroll 1
    for (int e = 0; e < NEPOCH; ++e) {
        if (e == 0) {
            #pragma unroll
            for (int s = 0; s < 3; ++s) {
                const float v = xn[s];
                S[s] = St{ v, v, 0.f, 0.f, 0.f, v };
            }
        } else {
            // ring sites: reload authoritative state published last epoch.
            // Own sites keep their fp32 registers (never reloaded).
            const size_t sl = (size_t)((e - 1) & 1) * NSITES;
            #pragma unroll
            for (int s = 0; s < 3; ++s) {
                if (!own[s]) {
                    const unsigned long long d1 =
                        __hip_atomic_load(&D1[sl + gidx[s]], __ATOMIC_RELAXED, AGENT);
                    const unsigned lo = (unsigned)d1, hi = (unsigned)(d1 >> 32);
                    float pv = 0.f, x0v = 0.f;
                    if (comp[s]) {
                        P2 d2;
                        d2.u = __hip_atomic_load(&D2[sl + gidx[s]], __ATOMIC_RELAXED, AGENT);
                        pv = d2.f[0]; x0v = d2.f[1];
                    }
                    S[s] = St{ x0v, pv, bf_hi(lo), bf_lo(hi), bf_hi(hi), bf_lo(lo) };
                }
            }
        }

        substep(3); substep(2); substep(1); substep(0);

        if (e < NEPOCH - 1) {
            const size_t sw = (size_t)(e & 1) * NSITES;
            #pragma unroll
            for (int s = 0; s < 3; ++s) {
                if (own[s]) {
                    __hip_atomic_store(&D1[sw + gidx[s]],
                        pk_bf4(S[s].xb, S[s].q0, S[s].q1, S[s].q2),
                        __ATOMIC_RELAXED, AGENT);
                    P2 w; w.f[0] = S[s].p; w.f[1] = S[s].x0;
                    __hip_atomic_store(&D2[sw + gidx[s]], w.u, __ATOMIC_RELAXED, AGENT);
                }
            }
            gridbar(bar, (unsigned)(e + 1));
        }
    }

    #pragma unroll
    for (int s = 0; s < 3; ++s) {
        if (own[s]) out[gidx[s]] = S[s].x0;   // x1 after 128 steps
    }
}

extern "C" void kernel_launch(void* const* d_in, const int* in_sizes, int n_in,
                              void* d_out, int out_size, void* d_ws, size_t ws_size,
                              hipStream_t stream) {
    const float* x   = (const float*)d_in[0];
    const float* lam = (const float*)d_in[1];
    const float* tau = (const float*)d_in[2];
    const float* sig = (const float*)d_in[3];
    const float* th  = (const float*)d_in[4];
    float* out = (float*)d_out;

    // ws layout: D1 (2 slots u64, 4 MB), D2 (2 slots u64, 4 MB), barrier block
    unsigned long long* D1 = (unsigned long long*)d_ws;
    unsigned long long* D2 = D1 + 2 * (size_t)NSITES;
    unsigned* bar = (unsigned*)(D2 + 2 * (size_t)NSITES);

    // ws is poisoned to 0xAA before every timed call: zero the barrier block
    hipMemsetAsync(bar, 0, 4096, stream);

    void* args[] = {
        (void*)&x, (void*)&lam, (void*)&tau, (void*)&sig, (void*)&th,
        (void*)&D1, (void*)&D2, (void*)&bar, (void*)&out
    };
    hipLaunchCooperativeKernel((const void*)pdhg_persist,
                               dim3(NBLK), dim3(1024), args, 0, stream);
}

// Round 16
// 354.545 us; speedup vs baseline: 1.0701x; 1.0701x over previous
//
#include <hip/hip_runtime.h>
#include <math.h>

// (P, C, NX, NY, NT) = (2, 1, 128, 128, 8), T = 128
// Layout: idx = pp<<17 | X<<10 | Y<<3 | T
#define NSITES (2 * 128 * 128 * 8)      // 262144
#define NBLK   256                      // 16 bx * 8 by * 2 pp
#define NEPOCH 32                       // 32 epochs x 4 fused steps = 128
#define TLX    16                       // staged tile x: 8 own + 4+4 halo
#define TLY    24                       // staged tile y: 16 own + 4+4 halo
#define TSITES (TLX * TLY * 8)          // 3072 staged sites, 3 per thread

#define AGENT __HIP_MEMORY_SCOPE_AGENT

union P2 { float f[2]; unsigned long long u; };
struct St { float x0, p, q0, q1, q2, xb; };

__device__ __forceinline__ unsigned bf_rnd(float v) {
    const unsigned u = __float_as_uint(v);
    return (u + 0x7FFFu + ((u >> 16) & 1u)) >> 16;
}
__device__ __forceinline__ float bf_lo(unsigned p) { return __uint_as_float(p << 16); }
__device__ __forceinline__ float bf_hi(unsigned p) { return __uint_as_float(p & 0xFFFF0000u); }
__device__ __forceinline__ unsigned pk_bf2(float lo, float hi) {
    return bf_rnd(lo) | (bf_rnd(hi) << 16);
}
__device__ __forceinline__ unsigned long long pk_bf4(float a, float b, float c, float d) {
    return (unsigned long long)pk_bf2(a, b) | ((unsigned long long)pk_bf2(c, d) << 32);
}

// R3's proven tree barrier: 1 poller/block, s_sleep backoff, 16-block leaves.
__device__ __forceinline__ void gridbar(unsigned* __restrict__ bar, unsigned step) {
    __syncthreads();  // drains each wave's vmcnt: agent stores are at the coherence point
    if (threadIdx.x == 0) {
        unsigned* leaf = bar + ((blockIdx.x >> 4) << 4);
        unsigned* root = bar + 512;
        unsigned* flag = bar + 576;
        const unsigned old = __hip_atomic_fetch_add(leaf, 1u, __ATOMIC_RELEASE, AGENT);
        if (old + 1u == 16u * step) {
            const unsigned r = __hip_atomic_fetch_add(root, 1u, __ATOMIC_RELAXED, AGENT);
            if (r + 1u == 16u * step) {
                __hip_atomic_store(flag, step, __ATOMIC_RELAXED, AGENT);
            }
        }
        while (__hip_atomic_load(flag, __ATOMIC_RELAXED, AGENT) < step) {
            __builtin_amdgcn_s_sleep(1);
        }
    }
    __syncthreads();
}

// Persistent kernel (PLAIN launch): 32 epochs x (R14's 4-step 2-D tile).
// Co-residency is guaranteed by capacity: 256 blocks on 256 CUs, each block
// 16 waves / 48 KB LDS / ~40 VGPR -> >=2 blocks/CU capacity, so the spin
// barrier cannot deadlock. Own-tile state + read-only fields live in
// registers for the whole run; only the halo ring crosses the MALL each
// epoch (D1 bf16x4 8B, D2 ring bf16x2 4B).
__global__ __launch_bounds__(1024, 4) void pdhg_persist(
    const float* __restrict__ x,
    const float* __restrict__ lam,
    const float* __restrict__ tau_p,
    const float* __restrict__ sigma_p,
    const float* __restrict__ theta_p,
    unsigned long long* __restrict__ D1,   // 2 slots * NSITES bf16x4 {xb,q0,q1,q2}
    unsigned* __restrict__ D2,             // 2 slots * NSITES bf16x2 {p,x0}
    unsigned* __restrict__ bar,
    float* __restrict__ out)
{
    __shared__ float    Lxb[2][TSITES];   // 24 KB
    __shared__ unsigned Lqq[2][TSITES];   // 24 KB  bf16x2 {q0,q1}

    // XCD-arc swizzle (L2-locality heuristic only)
    const int b  = 32 * (blockIdx.x & 7) + (blockIdx.x >> 3);
    const int u  = threadIdx.x;
    const int pp = b >> 7;
    const int rr = b & 127;
    const int bx = rr >> 3;        // [0,16)
    const int by = rr & 7;         // [0,8)

    const int T    = u & 7;
    const int lx   = (u >> 3) & 15;    // [0,16)
    const int ly0  = u >> 7;           // [0,8); slice s has ly = ly0 + 8s
    const int lane = u & 63;
    const int src_tm = (lane & 0x38) | ((T + 7) & 7);
    const int src_tp = (lane & 0x38) | ((T + 1) & 7);

    const int X  = ((bx << 3) + lx - 4) & 127;
    const int Xm = (X + 127) & 127;

    const bool cx = (lx >= 1 && lx < 15);

    int gidx[3];
    bool comp[3], own[3];
    float xn[3], lamc[3], lamx[3], lamy[3], lamt[3];
    #pragma unroll
    for (int s = 0; s < 3; ++s) {
        const int ly = ly0 + 8 * s;
        const int Y  = ((by << 4) + ly - 4) & 127;
        const int Ym = (Y + 127) & 127;
        gidx[s] = (pp << 17) | (X << 10) | (Y << 3) | T;
        const int gxm = (pp << 17) | (Xm << 10) | (Y  << 3) | T;
        const int gym = (pp << 17) | (X  << 10) | (Ym << 3) | T;
        comp[s] = cx && (ly >= 1) && (ly < 23);
        own[s]  = (lx >= 4 && lx < 12 && ly >= 4 && ly < 20);
        xn[s]   = x[gidx[s]];                       // loaded ONCE per kernel
        lamc[s] = comp[s] ? lam[gidx[s]] : 0.f;
        lamx[s] = comp[s] ? lam[gxm] : 0.f;
        lamy[s] = comp[s] ? lam[gym] : 0.f;
    }
    #pragma unroll
    for (int s = 0; s < 3; ++s) lamt[s] = __shfl(lamc[s], src_tm, 64);

    const float L = 3.605551275463989f;  // sqrt(13)
    const float s_sig = (1.f / (1.f + __expf(-sigma_p[0]))) / L;
    const float s_tau = (1.f / (1.f + __expf(-tau_p[0]))) / L;
    const float s_th  =  1.f / (1.f + __expf(-theta_p[0]));
    const float inv1s = 1.f / (1.f + s_sig);

    auto clip = [](float v, float l) { return fmaxf(-l, fminf(l, v)); };
    auto upd = [&](const St& s, float xn_,
                   float xbxp, float xbxm, float xbyp, float xbym,
                   float xbtp, float xbtm,
                   float q0xm, float q1ym, float q2tm,
                   float lc, float lX, float lY, float lT) -> St {
        const float pn  = (s.p + s_sig * (s.xb - xn_)) * inv1s;
        const float q0n = clip(s.q0 + s_sig * (xbxp - s.xb), lc);
        const float q1n = clip(s.q1 + s_sig * (xbyp - s.xb), lc);
        const float q2n = clip(s.q2 + s_sig * (xbtp - s.xb), lc);
        const float q0m = clip(q0xm + s_sig * (s.xb - xbxm), lX);
        const float q1m = clip(q1ym + s_sig * (s.xb - xbym), lY);
        const float q2m = clip(q2tm + s_sig * (s.xb - xbtm), lT);
        const float dv  = (q0m - q0n) + (q1m - q1n) + (q2m - q2n);
        const float x1  = s.x0 - s_tau * (pn + dv);
        return St{ x1, pn, q0n, q1n, q2n, x1 + s_th * (x1 - s.x0) };
    };

    St S[3];

    // substep (R14-proven): compute lx in [4-h,12+h), ly in [4-h,20+h);
    // store-mask = region(h+1); double-buffered LDS, one barrier per sub-step.
    auto substep = [&](int h) {
        const int pb = h & 1;
        #pragma unroll
        for (int s = 0; s < 3; ++s) {
            const int ly = ly0 + 8 * s;
            if (ly < 3 - h || ly >= 21 + h) continue;        // wave-uniform skip
            if (lx >= 3 - h && lx < 13 + h) {
                const int f = u + (s << 10);
                Lxb[pb][f] = S[s].xb;
                Lqq[pb][f] = pk_bf2(S[s].q0, S[s].q1);
            }
        }
        __syncthreads();
        #pragma unroll
        for (int s = 0; s < 3; ++s) {
            const int ly = ly0 + 8 * s;
            if (ly < 4 - h || ly >= 20 + h) continue;        // wave-uniform skip
            const float xbtp = __shfl(S[s].xb, src_tp, 64);
            const float xbtm = __shfl(S[s].xb, src_tm, 64);
            const float q2tm = __shfl(S[s].q2, src_tm, 64);
            if (lx >= 4 - h && lx < 12 + h) {
                const int f = u + (s << 10);
                S[s] = upd(S[s], xn[s],
                           Lxb[pb][f + 8], Lxb[pb][f - 8],
                           Lxb[pb][f + 128], Lxb[pb][f - 128],
                           xbtp, xbtm,
                           bf_lo(Lqq[pb][f - 8]), bf_hi(Lqq[pb][f - 128]), q2tm,
                           lamc[s], lamx[s], lamy[s], lamt[s]);
            }
        }
    };

    #pragma unroll 1
    for (int e = 0; e < NEPOCH; ++e) {
        if (e == 0) {
            #pragma unroll
            for (int s = 0; s < 3; ++s) {
                const float v = xn[s];
                S[s] = St{ v, v, 0.f, 0.f, 0.f, v };
            }
        } else {
            // ring sites: reload authoritative state published last epoch.
            // Own sites keep their fp32 registers (never reloaded).
            const size_t sl = (size_t)((e - 1) & 1) * NSITES;
            #pragma unroll
            for (int s = 0; s < 3; ++s) {
                if (!own[s]) {
                    const unsigned long long d1 =
                        __hip_atomic_load(&D1[sl + gidx[s]], __ATOMIC_RELAXED, AGENT);
                    const unsigned lo = (unsigned)d1, hi = (unsigned)(d1 >> 32);
                    float pv = 0.f, x0v = 0.f;
                    if (comp[s]) {
                        const unsigned d2 =
                            __hip_atomic_load(&D2[sl + gidx[s]], __ATOMIC_RELAXED, AGENT);
                        pv = bf_lo(d2); x0v = bf_hi(d2);
                    }
                    S[s] = St{ x0v, pv, bf_hi(lo), bf_lo(hi), bf_hi(hi), bf_lo(lo) };
                }
            }
        }

        substep(3); substep(2); substep(1); substep(0);

        if (e < NEPOCH - 1) {
            const size_t sw = (size_t)(e & 1) * NSITES;
            #pragma unroll
            for (int s = 0; s < 3; ++s) {
                if (own[s]) {
                    __hip_atomic_store(&D1[sw + gidx[s]],
                        pk_bf4(S[s].xb, S[s].q0, S[s].q1, S[s].q2),
                        __ATOMIC_RELAXED, AGENT);
                    __hip_atomic_store(&D2[sw + gidx[s]],
                        pk_bf2(S[s].p, S[s].x0),
                        __ATOMIC_RELAXED, AGENT);
                }
            }
            gridbar(bar, (unsigned)(e + 1));
        }
    }

    #pragma unroll
    for (int s = 0; s < 3; ++s) {
        if (own[s]) out[gidx[s]] = S[s].x0;   // x1 after 128 steps
    }
}

extern "C" void kernel_launch(void* const* d_in, const int* in_sizes, int n_in,
                              void* d_out, int out_size, void* d_ws, size_t ws_size,
                              hipStream_t stream) {
    const float* x   = (const float*)d_in[0];
    const float* lam = (const float*)d_in[1];
    const float* tau = (const float*)d_in[2];
    const float* sig = (const float*)d_in[3];
    const float* th  = (const float*)d_in[4];
    float* out = (float*)d_out;

    // ws layout: D1 (2 slots u64, 4 MB), D2 (2 slots u32, 2 MB), barrier block
    unsigned long long* D1 = (unsigned long long*)d_ws;
    unsigned* D2 = (unsigned*)(D1 + 2 * (size_t)NSITES);
    unsigned* bar = D2 + 2 * (size_t)NSITES;

    // ws is poisoned to 0xAA before every timed call: zero the barrier block
    hipMemsetAsync(bar, 0, 4096, stream);

    // Plain launch (not cooperative): 256 blocks on 256 CUs with >=2 blocks/CU
    // capacity guarantees full co-residency for the spin barrier.
    pdhg_persist<<<dim3(NBLK), dim3(1024), 0, stream>>>(
        x, lam, tau, sig, th, D1, D2, bar, out);
}

// Round 17
// 331.438 us; speedup vs baseline: 1.1447x; 1.0697x over previous
//
#include <hip/hip_runtime.h>
#include <math.h>

// (P, C, NX, NY, NT) = (2, 1, 128, 128, 8), T = 128
// Layout: idx = pp<<17 | X<<10 | Y<<3 | T
#define NSITES (2 * 128 * 128 * 8)      // 262144
#define NBLK   256                      // 16 bx * 8 by * 2 pp
#define NSUP   32                       // 32 launches x 4 fused steps = 128
#define TLX    16                       // staged tile x: 8 own + 4+4 halo
#define TLY    24                       // staged tile y: 16 own + 4+4 halo
#define TSITES (TLX * TLY * 8)          // 3072 staged sites, 3 per thread

union P2 { float f[2]; unsigned long long u; };
struct St { float x0, p, q0, q1, q2, xb; };

// bf16 helpers (RNE). Every block rounds identical register values
// identically, so cross-block redundant-compute consistency is bitwise-exact.
__device__ __forceinline__ unsigned bf_rnd(float v) {
    const unsigned u = __float_as_uint(v);
    return (u + 0x7FFFu + ((u >> 16) & 1u)) >> 16;
}
__device__ __forceinline__ float bf_lo(unsigned p) { return __uint_as_float(p << 16); }
__device__ __forceinline__ float bf_hi(unsigned p) { return __uint_as_float(p & 0xFFFF0000u); }
__device__ __forceinline__ unsigned pk_bf2(float lo, float hi) {
    return bf_rnd(lo) | (bf_rnd(hi) << 16);
}
__device__ __forceinline__ unsigned long long pk_bf4(float a, float b, float c, float d) {
    return (unsigned long long)pk_bf2(a, b) | ((unsigned long long)pk_bf2(c, d) << 32);
}

// One launch = 4 PDHG steps, 2-D tiled (8x*16y*8t own, halo 4), redundancy
// 1.67x (R14 structure). State: u64 bf16x4 {xb,q0,q1,q2} + u32 bf16x2 {p,x0}.
// LDS double-buffered (xb fp32 + {q0,q1} bf16x2 = 24 KB/buf): ONE barrier per
// sub-step. Cross-launch halo via plain cached loads/stores (launch boundary
// = free device-wide coherence).
template <bool FIRST, bool LAST>
__global__ __launch_bounds__(1024, 4) void pdhg_tile(
    const float* __restrict__ x,
    const float* __restrict__ lam,
    const float* __restrict__ tau_p,
    const float* __restrict__ sigma_p,
    const float* __restrict__ theta_p,
    const unsigned long long* __restrict__ inD1,   // bf16x4 {xb,q0,q1,q2}
    const unsigned* __restrict__ inD2,             // bf16x2 {p,x0}
    unsigned long long* __restrict__ outD1,
    unsigned* __restrict__ outD2,
    float* __restrict__ out_final)
{
    __shared__ float    Lxb[2][TSITES];   // 24 KB
    __shared__ unsigned Lqq[2][TSITES];   // 24 KB  bf16x2 {q0,q1}

    // XCD-arc swizzle (L2-locality heuristic only)
    const int b  = 32 * (blockIdx.x & 7) + (blockIdx.x >> 3);
    const int u  = threadIdx.x;
    const int pp = b >> 7;
    const int rr = b & 127;
    const int bx = rr >> 3;        // [0,16)
    const int by = rr & 7;         // [0,8)

    const int T    = u & 7;
    const int lx   = (u >> 3) & 15;    // [0,16), constant per thread
    const int ly0  = u >> 7;           // [0,8); slice s has ly = ly0 + 8s
    const int lane = u & 63;
    const int src_tm = (lane & 0x38) | ((T + 7) & 7);
    const int src_tp = (lane & 0x38) | ((T + 1) & 7);

    const int X  = ((bx << 3) + lx - 4) & 127;
    const int Xm = (X + 127) & 127;

    const bool cx = (lx >= 1 && lx < 15);   // x-extent of widest computed region

    int gidx[3];
    bool comp[3];                            // site in 14x22 max-computed region
    float xn[3], lamc[3], lamx[3], lamy[3], lamt[3];
    #pragma unroll
    for (int s = 0; s < 3; ++s) {
        const int ly = ly0 + 8 * s;
        const int Y  = ((by << 4) + ly - 4) & 127;
        const int Ym = (Y + 127) & 127;
        gidx[s] = (pp << 17) | (X << 10) | (Y << 3) | T;
        const int gxm = (pp << 17) | (Xm << 10) | (Y  << 3) | T;
        const int gym = (pp << 17) | (X  << 10) | (Ym << 3) | T;
        comp[s] = cx && (ly >= 1) && (ly < 23);
        xn[s]   = (FIRST || comp[s]) ? x[gidx[s]] : 0.f;   // FIRST inits xb=xn everywhere
        lamc[s] = comp[s] ? lam[gidx[s]] : 0.f;
        lamx[s] = comp[s] ? lam[gxm] : 0.f;
        lamy[s] = comp[s] ? lam[gym] : 0.f;
    }
    #pragma unroll
    for (int s = 0; s < 3; ++s) lamt[s] = __shfl(lamc[s], src_tm, 64);

    const float L = 3.605551275463989f;  // sqrt(13)
    const float s_sig = (1.f / (1.f + __expf(-sigma_p[0]))) / L;
    const float s_tau = (1.f / (1.f + __expf(-tau_p[0]))) / L;
    const float s_th  =  1.f / (1.f + __expf(-theta_p[0]));
    const float inv1s = 1.f / (1.f + s_sig);

    St S[3];
    if (FIRST) {
        #pragma unroll
        for (int s = 0; s < 3; ++s) {
            const float v = xn[s];
            S[s] = St{ v, v, 0.f, 0.f, 0.f, v };
        }
    } else {
        #pragma unroll
        for (int s = 0; s < 3; ++s) {
            const unsigned long long d1 = inD1[gidx[s]];
            const unsigned lo = (unsigned)d1, hi = (unsigned)(d1 >> 32);
            float pv = 0.f, x0v = 0.f;
            if (comp[s]) {                      // {p,x0} consumed only if computed
                const unsigned d2 = inD2[gidx[s]];
                pv = bf_lo(d2); x0v = bf_hi(d2);
            }
            S[s] = St{ x0v, pv, bf_hi(lo), bf_lo(hi), bf_hi(hi), bf_lo(lo) };
        }
    }

    auto clip = [](float v, float l) { return fmaxf(-l, fminf(l, v)); };
    auto upd = [&](const St& s, float xn_,
                   float xbxp, float xbxm, float xbyp, float xbym,
                   float xbtp, float xbtm,
                   float q0xm, float q1ym, float q2tm,
                   float lc, float lX, float lY, float lT) -> St {
        const float pn  = (s.p + s_sig * (s.xb - xn_)) * inv1s;
        const float q0n = clip(s.q0 + s_sig * (xbxp - s.xb), lc);
        const float q1n = clip(s.q1 + s_sig * (xbyp - s.xb), lc);
        const float q2n = clip(s.q2 + s_sig * (xbtp - s.xb), lc);
        const float q0m = clip(q0xm + s_sig * (s.xb - xbxm), lX);
        const float q1m = clip(q1ym + s_sig * (s.xb - xbym), lY);
        const float q2m = clip(q2tm + s_sig * (s.xb - xbtm), lT);
        const float dv  = (q0m - q0n) + (q1m - q1n) + (q2m - q2n);
        const float x1  = s.x0 - s_tau * (pn + dv);
        return St{ x1, pn, q0n, q1n, q2n, x1 + s_th * (x1 - s.x0) };
    };

    // one fused sub-step: compute lx in [4-h,12+h), ly in [4-h,20+h)
    // store-mask = region(h)+1-ring = region(h+1): [3-h,13+h) x [3-h,21+h)
    // Double-buffered LDS (pb = h&1): one barrier per sub-step.
    auto substep = [&](int h) {
        const int pb = h & 1;
        #pragma unroll
        for (int s = 0; s < 3; ++s) {
            const int ly = ly0 + 8 * s;
            if (ly < 3 - h || ly >= 21 + h) continue;        // wave-uniform skip
            if (lx >= 3 - h && lx < 13 + h) {                // per-lane mask
                const int f = u + (s << 10);
                Lxb[pb][f] = S[s].xb;
                Lqq[pb][f] = pk_bf2(S[s].q0, S[s].q1);
            }
        }
        __syncthreads();
        #pragma unroll
        for (int s = 0; s < 3; ++s) {
            const int ly = ly0 + 8 * s;
            if (ly < 4 - h || ly >= 20 + h) continue;        // wave-uniform skip
            // shfl sources share (lx,ly): inside region(h+1) == store-mask(h),
            // hence their S registers are current (region-nesting invariant)
            const float xbtp = __shfl(S[s].xb, src_tp, 64);
            const float xbtm = __shfl(S[s].xb, src_tm, 64);
            const float q2tm = __shfl(S[s].q2, src_tm, 64);
            if (lx >= 4 - h && lx < 12 + h) {
                const int f = u + (s << 10);
                S[s] = upd(S[s], xn[s],
                           Lxb[pb][f + 8], Lxb[pb][f - 8],
                           Lxb[pb][f + 128], Lxb[pb][f - 128],
                           xbtp, xbtm,
                           bf_lo(Lqq[pb][f - 8]), bf_hi(Lqq[pb][f - 128]), q2tm,
                           lamc[s], lamx[s], lamy[s], lamt[s]);
            }
        }
    };

    substep(3);   // step 4g+1 on 14x22
    substep(2);   // step 4g+2 on 12x20
    substep(1);   // step 4g+3 on 10x18
    substep(0);   // step 4g+4 on  8x16 (own)

    // write authoritative own sites only
    #pragma unroll
    for (int s = 0; s < 3; ++s) {
        const int ly = ly0 + 8 * s;
        if (lx >= 4 && lx < 12 && ly >= 4 && ly < 20) {
            if (LAST) {
                out_final[gidx[s]] = S[s].x0;
            } else {
                outD1[gidx[s]] = pk_bf4(S[s].xb, S[s].q0, S[s].q1, S[s].q2);
                outD2[gidx[s]] = pk_bf2(S[s].p, S[s].x0);
            }
        }
    }
}

extern "C" void kernel_launch(void* const* d_in, const int* in_sizes, int n_in,
                              void* d_out, int out_size, void* d_ws, size_t ws_size,
                              hipStream_t stream) {
    const float* x   = (const float*)d_in[0];
    const float* lam = (const float*)d_in[1];
    const float* tau = (const float*)d_in[2];
    const float* sig = (const float*)d_in[3];
    const float* th  = (const float*)d_in[4];
    float* out = (float*)d_out;

    // ws layout: D1 (2 slots u64, 4 MB), D2 (2 slots u32, 2 MB)
    unsigned long long* D1 = (unsigned long long*)d_ws;
    unsigned* D2 = (unsigned*)(D1 + 2 * (size_t)NSITES);

    dim3 grid(NBLK), block(1024);

    for (int g = 0; g < NSUP; ++g) {
        const size_t si = (size_t)((g + 1) & 1) * NSITES;  // read slot (prev write)
        const size_t so = (size_t)(g & 1) * NSITES;        // write slot
        const unsigned long long* i1 = D1 + si;
        const unsigned* i2 = D2 + si;
        unsigned long long* o1 = D1 + so;
        unsigned* o2 = D2 + so;
        if (g == 0) {
            pdhg_tile<true, false><<<grid, block, 0, stream>>>(
                x, lam, tau, sig, th, i1, i2, o1, o2, out);
        } else if (g == NSUP - 1) {
            pdhg_tile<false, true><<<grid, block, 0, stream>>>(
                x, lam, tau, sig, th, i1, i2, o1, o2, out);
        } else {
            pdhg_tile<false, false><<<grid, block, 0, stream>>>(
                x, lam, tau, sig, th, i1, i2, o1, o2, out);
        }
    }
}

// Round 18
// 313.216 us; speedup vs baseline: 1.2113x; 1.0582x over previous
//
#include <hip/hip_runtime.h>
#include <math.h>

// (P, C, NX, NY, NT) = (2, 1, 128, 128, 8), T = 128
// Layout: idx = pp<<17 | X<<10 | Y<<3 | T
#define NSITES (2 * 128 * 128 * 8)      // 262144
#define NBLK   256                      // 16 bx * 8 by * 2 pp
#define NSUP   32                       // 32 launches x 4 fused steps = 128
#define TLX    16                       // staged tile x: 8 own + 4+4 halo
#define TLY    24                       // staged tile y: 16 own + 4+4 halo
#define TSITES (TLX * TLY * 8)          // 3072 staged sites, 3 per thread

union P2 { float f[2]; unsigned long long u; };
struct St { float x0, p, q0, q1, q2, xb; };

// bf16 helpers (RNE). Every block rounds identical register values
// identically, so cross-block redundant-compute consistency is bitwise-exact.
__device__ __forceinline__ unsigned bf_rnd(float v) {
    const unsigned u = __float_as_uint(v);
    return (u + 0x7FFFu + ((u >> 16) & 1u)) >> 16;
}
__device__ __forceinline__ float bf_lo(unsigned p) { return __uint_as_float(p << 16); }
__device__ __forceinline__ float bf_hi(unsigned p) { return __uint_as_float(p & 0xFFFF0000u); }
__device__ __forceinline__ unsigned pk_bf2(float lo, float hi) {
    return bf_rnd(lo) | (bf_rnd(hi) << 16);
}
__device__ __forceinline__ unsigned long long pk_bf4(float a, float b, float c, float d) {
    return (unsigned long long)pk_bf2(a, b) | ((unsigned long long)pk_bf2(c, d) << 32);
}

// One launch = 4 PDHG steps, 2-D tiled (8x*16y*8t own, halo 4), redundancy
// 1.67x (R14 structure — session best, 313.6 us). State: u64 bf16x4
// {xb,q0,q1,q2} + u64 fp32x2 {p,x0} (x0 accumulator exact — bf16-packing
// this stream regressed both time and absmax, R17). LDS double-buffered
// (xb fp32 + {q0,q1} bf16x2 = 24 KB/buf): ONE barrier per sub-step.
// Cross-launch halo via plain cached loads/stores (launch boundary = free
// device-wide coherence).
template <bool FIRST, bool LAST>
__global__ __launch_bounds__(1024, 4) void pdhg_tile(
    const float* __restrict__ x,
    const float* __restrict__ lam,
    const float* __restrict__ tau_p,
    const float* __restrict__ sigma_p,
    const float* __restrict__ theta_p,
    const unsigned long long* __restrict__ inD1,   // bf16x4 {xb,q0,q1,q2}
    const unsigned long long* __restrict__ inD2,   // fp32x2 {p,x0}
    unsigned long long* __restrict__ outD1,
    unsigned long long* __restrict__ outD2,
    float* __restrict__ out_final)
{
    __shared__ float    Lxb[2][TSITES];   // 24 KB
    __shared__ unsigned Lqq[2][TSITES];   // 24 KB  bf16x2 {q0,q1}

    // XCD-arc swizzle (L2-locality heuristic only)
    const int b  = 32 * (blockIdx.x & 7) + (blockIdx.x >> 3);
    const int u  = threadIdx.x;
    const int pp = b >> 7;
    const int rr = b & 127;
    const int bx = rr >> 3;        // [0,16)
    const int by = rr & 7;         // [0,8)

    const int T    = u & 7;
    const int lx   = (u >> 3) & 15;    // [0,16), constant per thread
    const int ly0  = u >> 7;           // [0,8); slice s has ly = ly0 + 8s
    const int lane = u & 63;
    const int src_tm = (lane & 0x38) | ((T + 7) & 7);
    const int src_tp = (lane & 0x38) | ((T + 1) & 7);

    const int X  = ((bx << 3) + lx - 4) & 127;
    const int Xm = (X + 127) & 127;

    const bool cx = (lx >= 1 && lx < 15);   // x-extent of widest computed region

    int gidx[3];
    bool comp[3];                            // site in 14x22 max-computed region
    float xn[3], lamc[3], lamx[3], lamy[3], lamt[3];
    #pragma unroll
    for (int s = 0; s < 3; ++s) {
        const int ly = ly0 + 8 * s;
        const int Y  = ((by << 4) + ly - 4) & 127;
        const int Ym = (Y + 127) & 127;
        gidx[s] = (pp << 17) | (X << 10) | (Y << 3) | T;
        const int gxm = (pp << 17) | (Xm << 10) | (Y  << 3) | T;
        const int gym = (pp << 17) | (X  << 10) | (Ym << 3) | T;
        comp[s] = cx && (ly >= 1) && (ly < 23);
        xn[s]   = (FIRST || comp[s]) ? x[gidx[s]] : 0.f;   // FIRST inits xb=xn everywhere
        lamc[s] = comp[s] ? lam[gidx[s]] : 0.f;
        lamx[s] = comp[s] ? lam[gxm] : 0.f;
        lamy[s] = comp[s] ? lam[gym] : 0.f;
    }
    #pragma unroll
    for (int s = 0; s < 3; ++s) lamt[s] = __shfl(lamc[s], src_tm, 64);

    const float L = 3.605551275463989f;  // sqrt(13)
    const float s_sig = (1.f / (1.f + __expf(-sigma_p[0]))) / L;
    const float s_tau = (1.f / (1.f + __expf(-tau_p[0]))) / L;
    const float s_th  =  1.f / (1.f + __expf(-theta_p[0]));
    const float inv1s = 1.f / (1.f + s_sig);

    St S[3];
    if (FIRST) {
        #pragma unroll
        for (int s = 0; s < 3; ++s) {
            const float v = xn[s];
            S[s] = St{ v, v, 0.f, 0.f, 0.f, v };
        }
    } else {
        #pragma unroll
        for (int s = 0; s < 3; ++s) {
            const unsigned long long d1 = inD1[gidx[s]];
            const unsigned lo = (unsigned)d1, hi = (unsigned)(d1 >> 32);
            P2 d2; d2.u = 0ull;
            if (comp[s]) d2.u = inD2[gidx[s]];   // {p,x0} consumed only if computed
            S[s] = St{ d2.f[1], d2.f[0], bf_hi(lo), bf_lo(hi), bf_hi(hi), bf_lo(lo) };
        }
    }

    auto clip = [](float v, float l) { return fmaxf(-l, fminf(l, v)); };
    auto upd = [&](const St& s, float xn_,
                   float xbxp, float xbxm, float xbyp, float xbym,
                   float xbtp, float xbtm,
                   float q0xm, float q1ym, float q2tm,
                   float lc, float lX, float lY, float lT) -> St {
        const float pn  = (s.p + s_sig * (s.xb - xn_)) * inv1s;
        const float q0n = clip(s.q0 + s_sig * (xbxp - s.xb), lc);
        const float q1n = clip(s.q1 + s_sig * (xbyp - s.xb), lc);
        const float q2n = clip(s.q2 + s_sig * (xbtp - s.xb), lc);
        const float q0m = clip(q0xm + s_sig * (s.xb - xbxm), lX);
        const float q1m = clip(q1ym + s_sig * (s.xb - xbym), lY);
        const float q2m = clip(q2tm + s_sig * (s.xb - xbtm), lT);
        const float dv  = (q0m - q0n) + (q1m - q1n) + (q2m - q2n);
        const float x1  = s.x0 - s_tau * (pn + dv);
        return St{ x1, pn, q0n, q1n, q2n, x1 + s_th * (x1 - s.x0) };
    };

    // one fused sub-step: compute lx in [4-h,12+h), ly in [4-h,20+h)
    // store-mask = region(h)+1-ring = region(h+1): [3-h,13+h) x [3-h,21+h)
    // Double-buffered LDS (pb = h&1): one barrier per sub-step. A thread may
    // write buf[pb^1] while another still reads buf[pb] two sub-steps ago —
    // distinct buffers, and two barriers separate reuse of the same buffer.
    auto substep = [&](int h) {
        const int pb = h & 1;
        #pragma unroll
        for (int s = 0; s < 3; ++s) {
            const int ly = ly0 + 8 * s;
            if (ly < 3 - h || ly >= 21 + h) continue;        // wave-uniform skip
            if (lx >= 3 - h && lx < 13 + h) {                // per-lane mask
                const int f = u + (s << 10);
                Lxb[pb][f] = S[s].xb;
                Lqq[pb][f] = pk_bf2(S[s].q0, S[s].q1);
            }
        }
        __syncthreads();
        #pragma unroll
        for (int s = 0; s < 3; ++s) {
            const int ly = ly0 + 8 * s;
            if (ly < 4 - h || ly >= 20 + h) continue;        // wave-uniform skip
            // shfl sources share (lx,ly): inside region(h+1) == store-mask(h),
            // hence their S registers are current (region-nesting invariant)
            const float xbtp = __shfl(S[s].xb, src_tp, 64);
            const float xbtm = __shfl(S[s].xb, src_tm, 64);
            const float q2tm = __shfl(S[s].q2, src_tm, 64);
            if (lx >= 4 - h && lx < 12 + h) {
                const int f = u + (s << 10);
                S[s] = upd(S[s], xn[s],
                           Lxb[pb][f + 8], Lxb[pb][f - 8],
                           Lxb[pb][f + 128], Lxb[pb][f - 128],
                           xbtp, xbtm,
                           bf_lo(Lqq[pb][f - 8]), bf_hi(Lqq[pb][f - 128]), q2tm,
                           lamc[s], lamx[s], lamy[s], lamt[s]);
            }
        }
    };

    substep(3);   // step 4g+1 on 14x22
    substep(2);   // step 4g+2 on 12x20
    substep(1);   // step 4g+3 on 10x18
    substep(0);   // step 4g+4 on  8x16 (own)

    // write authoritative own sites only
    #pragma unroll
    for (int s = 0; s < 3; ++s) {
        const int ly = ly0 + 8 * s;
        if (lx >= 4 && lx < 12 && ly >= 4 && ly < 20) {
            if (LAST) {
                out_final[gidx[s]] = S[s].x0;
            } else {
                outD1[gidx[s]] = pk_bf4(S[s].xb, S[s].q0, S[s].q1, S[s].q2);
                P2 w; w.f[0] = S[s].p; w.f[1] = S[s].x0;
                outD2[gidx[s]] = w.u;
            }
        }
    }
}

extern "C" void kernel_launch(void* const* d_in, const int* in_sizes, int n_in,
                              void* d_out, int out_size, void* d_ws, size_t ws_size,
                              hipStream_t stream) {
    const float* x   = (const float*)d_in[0];
    const float* lam = (const float*)d_in[1];
    const float* tau = (const float*)d_in[2];
    const float* sig = (const float*)d_in[3];
    const float* th  = (const float*)d_in[4];
    float* out = (float*)d_out;

    // ws layout: D1 (2 slots u64, 4 MB), D2 (2 slots u64, 4 MB)
    unsigned long long* D1 = (unsigned long long*)d_ws;
    unsigned long long* D2 = D1 + 2 * (size_t)NSITES;

    dim3 grid(NBLK), block(1024);

    for (int g = 0; g < NSUP; ++g) {
        const size_t si = (size_t)((g + 1) & 1) * NSITES;  // read slot (prev write)
        const size_t so = (size_t)(g & 1) * NSITES;        // write slot
        const unsigned long long *i1 = D1 + si, *i2 = D2 + si;
        unsigned long long *o1 = D1 + so, *o2 = D2 + so;
        if (g == 0) {
            pdhg_tile<true, false><<<grid, block, 0, stream>>>(
                x, lam, tau, sig, th, i1, i2, o1, o2, out);
        } else if (g == NSUP - 1) {
            pdhg_tile<false, true><<<grid, block, 0, stream>>>(
                x, lam, tau, sig, th, i1, i2, o1, o2, out);
        } else {
            pdhg_tile<false, false><<<grid, block, 0, stream>>>(
                x, lam, tau, sig, th, i1, i2, o1, o2, out);
        }
    }
}